// Round 15
// baseline (50.813 us; speedup 1.0000x reference)
//
#include <hip/hip_runtime.h>

#define HIDN 512
#define NHEAD 8
#define DHEAD 64
#define NB 4
#define NL 256
#define NROW 1024   // NB*NL

#define SCALE2 2.8853900817779268f   // 2*log2(e)
#define NEG2LOG2E -2.8853900817779268f

// workspace layout (float offsets)
#define WS_WQB 0
#define WS_WKB (WS_WQB + 131072)
#define WS_BQF (WS_WKB + 131072)
#define WS_BKF (WS_BQF + 512)
#define WS_XB  (WS_BKF + 512)          // X bf16 [1024][512] (written by attn)
#define WS_WVB (WS_XB + 262144)        // Wv bf16
#define WS_WOB (WS_WVB + 131072)       // Wo bf16
#define WS_EQ  (WS_WOB + 131072)
#define WS_EK  (WS_EQ + 524288)
#define WS_VF  (WS_EK + 524288)

typedef __attribute__((ext_vector_type(4))) float f32x4;
typedef __attribute__((ext_vector_type(8))) short bf16x8;

#define WROW 520   // padded LDS row stride (shorts): bank stride 4 -> 2-way (free)

__device__ __forceinline__ short f2bf(float x) {
  unsigned u = __float_as_uint(x);
  u += 0x7fffu + ((u >> 16) & 1u);   // RNE
  return (short)(u >> 16);
}

__device__ __forceinline__ bf16x8 cvt8(const float* __restrict__ p) {
  const float4 a = *reinterpret_cast<const float4*>(p);
  const float4 b = *reinterpret_cast<const float4*>(p + 4);
  bf16x8 o;
  o[0] = f2bf(a.x); o[1] = f2bf(a.y); o[2] = f2bf(a.z); o[3] = f2bf(a.w);
  o[4] = f2bf(b.x); o[5] = f2bf(b.y); o[6] = f2bf(b.z); o[7] = f2bf(b.w);
  return o;
}

// ---------------- prep: z=0/1 fold W1/W2 (+SCALE2) into Wq/Wk -> bf16; z=2/3 Wv/Wo cvt
__global__ __launch_bounds__(256) void prep(
    const float* __restrict__ Wq, const float* __restrict__ bq,
    const float* __restrict__ Wk, const float* __restrict__ bk,
    const float* __restrict__ W1, const float* __restrict__ b1,
    const float* __restrict__ W2, const float* __restrict__ b2,
    const float* __restrict__ Wv, const float* __restrict__ Wo,
    float* __restrict__ ws)
{
  const int z = blockIdx.z;
  if (z >= 2) {
    const float* src = (z == 2) ? Wv : Wo;
    short* dst = (short*)(ws + ((z == 2) ? WS_WVB : WS_WOB));
    const int i = (blockIdx.x * 256 + threadIdx.x) * 8;   // 128 blocks x 2048 = 262144
    *reinterpret_cast<bf16x8*>(dst + i) = cvt8(src + i);
    return;
  }

  const int c0 = (blockIdx.x & 3) * 128;
  const int y  = blockIdx.x >> 2;
  const int h  = y >> 2;
  const int ig = y & 3;                // 16-row group within head
  const int which = z;
  const float* Wsrc = which ? Wk : Wq;
  const float* bsrc = which ? bk : bq;
  const float* Wt   = which ? W2 : W1;
  const float* bt   = which ? b2 : b1;
  short* Wout = reinterpret_cast<short*>(ws + (which ? WS_WKB : WS_WQB));
  float* bout = ws + (which ? WS_BKF : WS_BQF);

  __shared__ float Wtl[16][68];
  for (int t = threadIdx.x; t < 16*64; t += 256)
    Wtl[t >> 6][t & 63] = Wt[(ig*16 + (t >> 6))*64 + (t & 63)];
  __syncthreads();

  const int c  = c0 + (threadIdx.x & 127);
  const int i0 = (threadIdx.x >> 7) * 8;   // local row base (0 or 8)
  float acc[8];
#pragma unroll
  for (int ii = 0; ii < 8; ++ii) acc[ii] = 0.f;

  for (int j0 = 0; j0 < 64; j0 += 4) {
    const float s0 = Wsrc[(h*64 + j0 + 0)*HIDN + c];
    const float s1 = Wsrc[(h*64 + j0 + 1)*HIDN + c];
    const float s2 = Wsrc[(h*64 + j0 + 2)*HIDN + c];
    const float s3 = Wsrc[(h*64 + j0 + 3)*HIDN + c];
#pragma unroll
    for (int ii = 0; ii < 8; ++ii) {
      const float4 wv4 = *reinterpret_cast<const float4*>(&Wtl[i0+ii][j0]);
      float a = acc[ii];
      a = fmaf(wv4.x, s0, a);
      a = fmaf(wv4.y, s1, a);
      a = fmaf(wv4.z, s2, a);
      a = fmaf(wv4.w, s3, a);
      acc[ii] = a;
    }
  }
#pragma unroll
  for (int ii = 0; ii < 8; ++ii)
    Wout[(h*64 + ig*16 + i0 + ii)*HIDN + c] = f2bf(acc[ii] * SCALE2);

  if (blockIdx.x == 0 && threadIdx.x < 16) {
    const int il = threadIdx.x;
    float a = bt[ig*16 + il];
    for (int j = 0; j < 64; ++j)
      a = fmaf(Wtl[il][j], bsrc[h*64 + j], a);
    bout[h*64 + ig*16 + il] = a * SCALE2;
  }
}

// stage 32 contiguous bf16 W-rows (32x512) into LDS with padded stride WROW
__device__ __forceinline__ void stage_w(short* __restrict__ Wl,
                                        const short* __restrict__ Wg /* row nb base */)
{
  const int t = threadIdx.x;
#pragma unroll
  for (int i = 0; i < 8; ++i) {
    const int linear = i*256 + t;           // 2048 chunks of 8 shorts
    const int row  = linear >> 6;           // 64 chunks per row
    const int cpos = (linear & 63) * 8;
    *reinterpret_cast<bf16x8*>(&Wl[row*WROW + cpos]) =
        *reinterpret_cast<const bf16x8*>(&Wg[row*HIDN + cpos]);
  }
  __syncthreads();
}

// ---------------- mfma_proj: C = A(f32, cvt in-reg) @ W(bf16,LDS)^T + bias ----------
// grid (16 bx, 16 by, 3 z), 256 thr. z=0 -> EQ=e^{2Qt}; z=1 -> EK; z=2 -> VF fragments.
// A is the RAW f32 input (q/k/v) converted per-fragment in the MFMA shadow; W is
// pre-converted bf16 (fold output or Wv) staged in LDS.
__global__ __launch_bounds__(256, 8) void mfma_proj(
    const float* __restrict__ q, const float* __restrict__ kin, const float* __restrict__ v,
    float* __restrict__ ws, const float* __restrict__ bv)
{
  const int z = blockIdx.z;
  const float* A; const short* W; const float* bias;
  if (z == 0)      { A = q;   W = (const short*)(ws + WS_WQB); bias = ws + WS_BQF; }
  else if (z == 1) { A = kin; W = (const short*)(ws + WS_WKB); bias = ws + WS_BKF; }
  else             { A = v;   W = (const short*)(ws + WS_WVB); bias = bv; }

  __shared__ __align__(16) short Wl[32*WROW];   // 33.3 KB
  const int nb = blockIdx.x * 32;
  stage_w(Wl, W + nb*HIDN);

  const int wid  = threadIdx.x >> 6;
  const int lane = threadIdx.x & 63;
  const int mt = blockIdx.y * 4 + wid;     // m-tile 0..63
  const float* aptr = A + (mt*16 + (lane & 15))*HIDN + (lane >> 4)*8;
  const short* wl0  = &Wl[(lane & 15)*WROW + (lane >> 4)*8];

  f32x4 acc[2] = {{0,0,0,0},{0,0,0,0}};
#pragma unroll 4
  for (int k0 = 0; k0 < HIDN; k0 += 32) {
    const bf16x8 af = cvt8(aptr + k0);
#pragma unroll
    for (int t = 0; t < 2; ++t)
      acc[t] = __builtin_amdgcn_mfma_f32_16x16x32_bf16(
          af, *reinterpret_cast<const bf16x8*>(wl0 + t*16*WROW + k0), acc[t], 0, 0, 0);
  }

  const int rbase = mt*16 + (lane >> 4)*4;
  if (z < 2) {
    float* dst = ws + (z == 0 ? WS_EQ : WS_EK);
#pragma unroll
    for (int t = 0; t < 2; ++t) {
      const int c = nb + t*16 + (lane & 15);
      const float bc = bias[c];
      const int hh = c >> 6, d = c & 63;
#pragma unroll
      for (int r = 0; r < 4; ++r) {
        const int R = rbase + r;
        dst[(((R >> 8)*NHEAD + hh)*NL + (R & 255))*DHEAD + d] =
            __builtin_amdgcn_exp2f(acc[t][r] + bc);
      }
    }
  } else {
    short* vf = reinterpret_cast<short*>(ws + WS_VF);
#pragma unroll
    for (int t = 0; t < 2; ++t) {
      const int c = nb + t*16 + (lane & 15);
      const float bc = bias[c];
      const int hh = c >> 6, d = c & 63;
#pragma unroll
      for (int r = 0; r < 4; ++r) {
        const int R = rbase + r;
        const int l = R & 255;
        const int bh = (R >> 8)*NHEAD + hh;
        const int tile = ((l >> 5) << 2) + (d >> 4);
        const int lanep = (((l >> 3) & 3) << 4) + (d & 15);
        vf[((bh*32 + tile)*64 + lanep)*8 + (l & 7)] = f2bf(acc[t][r] + bc);
      }
    }
  }
}

// ---------------- mfma_out: out = X(bf16) @ Wo(bf16)^T + bo, W-tile in LDS ----------
__global__ __launch_bounds__(256, 8) void mfma_out(
    float* __restrict__ ws, const float* __restrict__ bo, float* __restrict__ out)
{
  const short* A = (const short*)(ws + WS_XB);    // X bf16 (written by attn)
  const short* W = (const short*)(ws + WS_WOB);

  __shared__ __align__(16) short Wl[32*WROW];
  const int nb = blockIdx.x * 32;
  stage_w(Wl, W + nb*HIDN);

  const int wid  = threadIdx.x >> 6;
  const int lane = threadIdx.x & 63;
  const int mt = blockIdx.y * 4 + wid;
  const short* aptr = A + (mt*16 + (lane & 15))*HIDN + (lane >> 4)*8;
  const short* wl0  = &Wl[(lane & 15)*WROW + (lane >> 4)*8];

  f32x4 acc[2] = {{0,0,0,0},{0,0,0,0}};
#pragma unroll 4
  for (int k0 = 0; k0 < HIDN; k0 += 32) {
    const bf16x8 af = *reinterpret_cast<const bf16x8*>(aptr + k0);
#pragma unroll
    for (int t = 0; t < 2; ++t)
      acc[t] = __builtin_amdgcn_mfma_f32_16x16x32_bf16(
          af, *reinterpret_cast<const bf16x8*>(wl0 + t*16*WROW + k0), acc[t], 0, 0, 0);
  }

  const int rbase = mt*16 + (lane >> 4)*4;
#pragma unroll
  for (int t = 0; t < 2; ++t) {
    const int c = nb + t*16 + (lane & 15);
    const float bc = bo[c];
#pragma unroll
    for (int r = 0; r < 4; ++r)
      out[(rbase + r)*HIDN + c] = acc[t][r] + bc;
  }
}

// ---------------- attn: paired-rcp energy (SGPR Eq/va), no-max softmax, MFMA PV ------
// grid (32 bh, 16 qt): bid%8 XCD mapping pins bh==XCD (mod 8) -> EK/VF L2-resident.
__global__ __launch_bounds__(1024, 8) void attn_kernel(
    const float* __restrict__ eqB, const float* __restrict__ ekB,
    const short* __restrict__ vfB, const float* __restrict__ va_w,
    float* __restrict__ attn_out, short* __restrict__ xb)
{
  const int bh = blockIdx.x;
  const int qt = blockIdx.y;
  const int tid = threadIdx.x;

  __shared__ __align__(16) short aLb[8][64][8];      // P as bf16 A-fragments
  __shared__ __align__(16) float reds[4][4][4];      // [qgroup][wave][qi]

  const float* EKB = ekB + bh*NL*DHEAD;
  const short* VF  = vfB + bh*32*64*8;

  const int g  = tid >> 8;        // q-group: rows g*4 .. g*4+3 (wave-uniform)
  const int lk = tid & 255;
  const int wv = lk >> 6;
  const int l  = lk & 63;
  const float* EkRow = EKB + lk*DHEAD;
  const int g_u = __builtin_amdgcn_readfirstlane(g);
  const float* EqG = eqB + (bh*NL + qt*16 + g_u*4)*DHEAD;

  float acc[4];
#pragma unroll
  for (int qi = 0; qi < 4; ++qi) acc[qi] = 0.f;

#pragma unroll 1
  for (int d0 = 0; d0 < 64; d0 += 8) {
    const f32x4 ea = *reinterpret_cast<const f32x4*>(EkRow + d0);
    const f32x4 eb = *reinterpret_cast<const f32x4*>(EkRow + d0 + 4);
    const f32x4 vaA = *reinterpret_cast<const f32x4*>(va_w + d0);       // uniform -> SGPR
    const f32x4 vaB = *reinterpret_cast<const f32x4*>(va_w + d0 + 4);
#pragma unroll
    for (int qi = 0; qi < 4; ++qi) {
      const f32x4 qa = *reinterpret_cast<const f32x4*>(EqG + qi*DHEAD + d0);      // uniform
      const f32x4 qb = *reinterpret_cast<const f32x4*>(EqG + qi*DHEAD + d0 + 4);  // uniform
      const float t0 = fmaf(qa.x, ea.x, 1.0f);
      const float t1 = fmaf(qa.y, ea.y, 1.0f);
      const float t2 = fmaf(qa.z, ea.z, 1.0f);
      const float t3 = fmaf(qa.w, ea.w, 1.0f);
      const float t4 = fmaf(qb.x, eb.x, 1.0f);
      const float t5 = fmaf(qb.y, eb.y, 1.0f);
      const float t6 = fmaf(qb.z, eb.z, 1.0f);
      const float t7 = fmaf(qb.w, eb.w, 1.0f);
      float a = acc[qi];
      a = fmaf(fmaf(vaA.x, t1, vaA.y * t0), __builtin_amdgcn_rcpf(t0 * t1), a);
      a = fmaf(fmaf(vaA.z, t3, vaA.w * t2), __builtin_amdgcn_rcpf(t2 * t3), a);
      a = fmaf(fmaf(vaB.x, t5, vaB.y * t4), __builtin_amdgcn_rcpf(t4 * t5), a);
      a = fmaf(fmaf(vaB.z, t7, vaB.w * t6), __builtin_amdgcn_rcpf(t6 * t7), a);
      acc[qi] = a;
    }
  }

  float p[4];
#pragma unroll
  for (int qi = 0; qi < 4; ++qi)
    p[qi] = __builtin_amdgcn_exp2f(acc[qi] * NEG2LOG2E);

#pragma unroll
  for (int qi = 0; qi < 4; ++qi) {
    float s = p[qi];
#pragma unroll
    for (int off = 1; off < 64; off <<= 1)
      s += __shfl_xor(s, off);
    if (l == 0) reds[g][wv][qi] = s;
  }
  {
    const int kb2 = lk >> 5;
    const int lbase = ((lk >> 3) & 3) * 16;
    const int jb = lk & 7;
#pragma unroll
    for (int qi = 0; qi < 4; ++qi)
      aLb[kb2][lbase + g*4 + qi][jb] = f2bf(p[qi]);
  }
  __syncthreads();

  {
    f32x4 s4 = {0.f,0.f,0.f,0.f};
#pragma unroll
    for (int w2 = 0; w2 < 4; ++w2)
      s4 += *reinterpret_cast<const f32x4*>(&reds[g][w2][0]);
    float inv[4];
    inv[0] = __builtin_amdgcn_rcpf(s4.x); inv[1] = __builtin_amdgcn_rcpf(s4.y);
    inv[2] = __builtin_amdgcn_rcpf(s4.z); inv[3] = __builtin_amdgcn_rcpf(s4.w);
#pragma unroll
    for (int qi = 0; qi < 4; ++qi)
      attn_out[(bh*NL + qt*16 + g*4 + qi)*NL + lk] = p[qi] * inv[qi];

    const int wid = tid >> 6;
    if (wid < 4) {
      f32x4 pacc = {0.f,0.f,0.f,0.f};
#pragma unroll
      for (int kb2 = 0; kb2 < 8; ++kb2) {
        const bf16x8 af  = *reinterpret_cast<const bf16x8*>(&aLb[kb2][l][0]);
        const bf16x8 bff = *reinterpret_cast<const bf16x8*>(&VF[((kb2*4 + wid)*64 + l)*8]);
        pacc = __builtin_amdgcn_mfma_f32_16x16x32_bf16(af, bff, pacc, 0, 0, 0);
      }
      const int b_ = bh >> 3, hh = bh & 7;
      const int colv = hh*DHEAD + wid*16 + (l & 15);
#pragma unroll
      for (int r = 0; r < 4; ++r) {
        const int row = (l >> 4)*4 + r;
        const float stot = reds[row>>2][0][row&3] + reds[row>>2][1][row&3]
                         + reds[row>>2][2][row&3] + reds[row>>2][3][row&3];
        xb[(b_*NL + qt*16 + row)*HIDN + colv] = f2bf(pacc[r] * __builtin_amdgcn_rcpf(stot));
      }
    }
  }
}

extern "C" void kernel_launch(void* const* d_in, const int* in_sizes, int n_in,
                              void* d_out, int out_size, void* d_ws, size_t ws_size,
                              hipStream_t stream) {
  const float* q    = (const float*)d_in[0];
  const float* kin  = (const float*)d_in[1];
  const float* v    = (const float*)d_in[2];
  const float* Wq   = (const float*)d_in[3];
  const float* bq   = (const float*)d_in[4];
  const float* Wk   = (const float*)d_in[5];
  const float* bk   = (const float*)d_in[6];
  const float* Wv   = (const float*)d_in[7];
  const float* bv   = (const float*)d_in[8];
  const float* W1   = (const float*)d_in[9];
  const float* b1   = (const float*)d_in[10];
  const float* W2   = (const float*)d_in[11];
  const float* b2   = (const float*)d_in[12];
  const float* va_w = (const float*)d_in[13];
  const float* Wo   = (const float*)d_in[15];
  const float* bo   = (const float*)d_in[16];

  float* out = (float*)d_out;
  float* ws  = (float*)d_ws;
  float* attn = out + NROW*HIDN;   // output 1: attention [B,H,Lq,Lk]

  prep<<<dim3(128, 1, 4), 256, 0, stream>>>(Wq, bq, Wk, bk, W1, b1, W2, b2,
                                            Wv, Wo, ws);
  mfma_proj<<<dim3(16, 16, 3), 256, 0, stream>>>(q, kin, v, ws, bv);
  attn_kernel<<<dim3(32, 16), 1024, 0, stream>>>(
      ws + WS_EQ, ws + WS_EK, (const short*)(ws + WS_VF), va_w,
      attn, (short*)(ws + WS_XB));
  mfma_out<<<dim3(16, 16), 256, 0, stream>>>(ws, bo, out);
}

// Round 16
// 48.366 us; speedup vs baseline: 1.0506x; 1.0506x over previous
//
#include <hip/hip_runtime.h>

#define HIDN 512
#define NHEAD 8
#define DHEAD 64
#define NB 4
#define NL 256
#define NROW 1024   // NB*NL

#define SCALE2 2.8853900817779268f   // 2*log2(e)
#define NEG2LOG2E -2.8853900817779268f

// workspace layout (float offsets)
#define WS_WQB 0
#define WS_WKB (WS_WQB + 131072)
#define WS_BQF (WS_WKB + 131072)
#define WS_BKF (WS_BQF + 512)
#define WS_QBF (WS_BKF + 512)          // query bf16; reused as X bf16 after proj
#define WS_KBF (WS_QBF + 262144)
#define WS_VBF (WS_KBF + 262144)
#define WS_WVB (WS_VBF + 262144)
#define WS_WOB (WS_WVB + 131072)
#define WS_EQ  (WS_WOB + 131072)
#define WS_EK  (WS_EQ + 524288)
#define WS_VF  (WS_EK + 524288)

typedef __attribute__((ext_vector_type(4))) float f32x4;
typedef __attribute__((ext_vector_type(8))) short bf16x8;

#define WROW 520   // padded LDS row stride (shorts): bank stride 4 -> 2-way (free)

__device__ __forceinline__ short f2bf(float x) {
  unsigned u = __float_as_uint(x);
  u += 0x7fffu + ((u >> 16) & 1u);   // RNE
  return (short)(u >> 16);
}

// ---------------- prep: z=0/1 fold W1/W2 (+SCALE2) into Wq/Wk -> bf16; z=2..6 f32->bf16 copies
__global__ __launch_bounds__(256) void prep(
    const float* __restrict__ Wq, const float* __restrict__ bq,
    const float* __restrict__ Wk, const float* __restrict__ bk,
    const float* __restrict__ W1, const float* __restrict__ b1,
    const float* __restrict__ W2, const float* __restrict__ b2,
    const float* __restrict__ q, const float* __restrict__ k, const float* __restrict__ v,
    const float* __restrict__ Wv, const float* __restrict__ Wo,
    float* __restrict__ ws)
{
  const int z = blockIdx.z;
  if (z >= 2) {
    const int zz = z - 2;
    const float* src; short* dst; int n;
    if (zz == 0)      { src = q;  dst = (short*)(ws + WS_QBF); n = 524288; }
    else if (zz == 1) { src = k;  dst = (short*)(ws + WS_KBF); n = 524288; }
    else if (zz == 2) { src = v;  dst = (short*)(ws + WS_VBF); n = 524288; }
    else if (zz == 3) { src = Wv; dst = (short*)(ws + WS_WVB); n = 262144; }
    else              { src = Wo; dst = (short*)(ws + WS_WOB); n = 262144; }
    const int i = (blockIdx.x * 256 + threadIdx.x) * 8;
    if (i >= n) return;
    const float4 a = *reinterpret_cast<const float4*>(src + i);
    const float4 b = *reinterpret_cast<const float4*>(src + i + 4);
    bf16x8 o;
    o[0] = f2bf(a.x); o[1] = f2bf(a.y); o[2] = f2bf(a.z); o[3] = f2bf(a.w);
    o[4] = f2bf(b.x); o[5] = f2bf(b.y); o[6] = f2bf(b.z); o[7] = f2bf(b.w);
    *reinterpret_cast<bf16x8*>(dst + i) = o;
    return;
  }

  if (blockIdx.x >= 128) return;
  const int c0 = (blockIdx.x & 3) * 128;
  const int y  = blockIdx.x >> 2;
  const int h  = y >> 2;
  const int ig = y & 3;                // 16-row group within head
  const int which = z;
  const float* Wsrc = which ? Wk : Wq;
  const float* bsrc = which ? bk : bq;
  const float* Wt   = which ? W2 : W1;
  const float* bt   = which ? b2 : b1;
  short* Wout = reinterpret_cast<short*>(ws + (which ? WS_WKB : WS_WQB));
  float* bout = ws + (which ? WS_BKF : WS_BQF);

  __shared__ float Wtl[16][68];
  for (int t = threadIdx.x; t < 16*64; t += 256)
    Wtl[t >> 6][t & 63] = Wt[(ig*16 + (t >> 6))*64 + (t & 63)];
  __syncthreads();

  const int c  = c0 + (threadIdx.x & 127);
  const int i0 = (threadIdx.x >> 7) * 8;   // local row base (0 or 8)
  float acc[8];
#pragma unroll
  for (int ii = 0; ii < 8; ++ii) acc[ii] = 0.f;

  for (int j0 = 0; j0 < 64; j0 += 4) {
    const float s0 = Wsrc[(h*64 + j0 + 0)*HIDN + c];
    const float s1 = Wsrc[(h*64 + j0 + 1)*HIDN + c];
    const float s2 = Wsrc[(h*64 + j0 + 2)*HIDN + c];
    const float s3 = Wsrc[(h*64 + j0 + 3)*HIDN + c];
#pragma unroll
    for (int ii = 0; ii < 8; ++ii) {
      const float4 wv4 = *reinterpret_cast<const float4*>(&Wtl[i0+ii][j0]);
      float a = acc[ii];
      a = fmaf(wv4.x, s0, a);
      a = fmaf(wv4.y, s1, a);
      a = fmaf(wv4.z, s2, a);
      a = fmaf(wv4.w, s3, a);
      acc[ii] = a;
    }
  }
#pragma unroll
  for (int ii = 0; ii < 8; ++ii)
    Wout[(h*64 + ig*16 + i0 + ii)*HIDN + c] = f2bf(acc[ii] * SCALE2);

  if (blockIdx.x == 0 && threadIdx.x < 16) {
    const int il = threadIdx.x;
    float a = bt[ig*16 + il];
    for (int j = 0; j < 64; ++j)
      a = fmaf(Wtl[il][j], bsrc[h*64 + j], a);
    bout[h*64 + ig*16 + il] = a * SCALE2;
  }
}

// stage 32 contiguous bf16 W-rows (32x512) into LDS with padded stride WROW
__device__ __forceinline__ void stage_w(short* __restrict__ Wl,
                                        const short* __restrict__ Wg /* row nb base */)
{
  const int t = threadIdx.x;
#pragma unroll
  for (int i = 0; i < 8; ++i) {
    const int linear = i*256 + t;           // 2048 chunks of 8 shorts
    const int row  = linear >> 6;           // 64 chunks per row
    const int cpos = (linear & 63) * 8;
    *reinterpret_cast<bf16x8*>(&Wl[row*WROW + cpos]) =
        *reinterpret_cast<const bf16x8*>(&Wg[row*HIDN + cpos]);
  }
  __syncthreads();
}

// ---------------- mfma_proj: C = A(bf16) @ W(bf16)^T + bias, W-tile in LDS ----------
// grid (16 bx, 16 by, 3 z), 256 thr. z=0 -> EQ=e^{2Qt}; z=1 -> EK; z=2 -> VF fragments.
__global__ __launch_bounds__(256, 8) void mfma_proj(float* __restrict__ ws, const float* __restrict__ bv)
{
  const int z = blockIdx.z;
  const short* A; const short* W; const float* bias;
  if (z == 0)      { A = (const short*)(ws + WS_QBF); W = (const short*)(ws + WS_WQB); bias = ws + WS_BQF; }
  else if (z == 1) { A = (const short*)(ws + WS_KBF); W = (const short*)(ws + WS_WKB); bias = ws + WS_BKF; }
  else             { A = (const short*)(ws + WS_VBF); W = (const short*)(ws + WS_WVB); bias = bv; }

  __shared__ __align__(16) short Wl[32*WROW];   // 33.3 KB
  const int nb = blockIdx.x * 32;
  stage_w(Wl, W + nb*HIDN);

  const int wid  = threadIdx.x >> 6;
  const int lane = threadIdx.x & 63;
  const int mt = blockIdx.y * 4 + wid;     // m-tile 0..63
  const short* aptr = A + (mt*16 + (lane & 15))*HIDN + (lane >> 4)*8;
  const short* wl0  = &Wl[(lane & 15)*WROW + (lane >> 4)*8];

  f32x4 acc[2] = {{0,0,0,0},{0,0,0,0}};
#pragma unroll 4
  for (int k0 = 0; k0 < HIDN; k0 += 32) {
    const bf16x8 af = *reinterpret_cast<const bf16x8*>(aptr + k0);
#pragma unroll
    for (int t = 0; t < 2; ++t)
      acc[t] = __builtin_amdgcn_mfma_f32_16x16x32_bf16(
          af, *reinterpret_cast<const bf16x8*>(wl0 + t*16*WROW + k0), acc[t], 0, 0, 0);
  }

  const int rbase = mt*16 + (lane >> 4)*4;
  if (z < 2) {
    float* dst = ws + (z == 0 ? WS_EQ : WS_EK);
#pragma unroll
    for (int t = 0; t < 2; ++t) {
      const int c = nb + t*16 + (lane & 15);
      const float bc = bias[c];
      const int hh = c >> 6, d = c & 63;
#pragma unroll
      for (int r = 0; r < 4; ++r) {
        const int R = rbase + r;
        dst[(((R >> 8)*NHEAD + hh)*NL + (R & 255))*DHEAD + d] =
            __builtin_amdgcn_exp2f(acc[t][r] + bc);
      }
    }
  } else {
    short* vf = reinterpret_cast<short*>(ws + WS_VF);
#pragma unroll
    for (int t = 0; t < 2; ++t) {
      const int c = nb + t*16 + (lane & 15);
      const float bc = bias[c];
      const int hh = c >> 6, d = c & 63;
#pragma unroll
      for (int r = 0; r < 4; ++r) {
        const int R = rbase + r;
        const int l = R & 255;
        const int bh = (R >> 8)*NHEAD + hh;
        const int tile = ((l >> 5) << 2) + (d >> 4);
        const int lanep = (((l >> 3) & 3) << 4) + (d & 15);
        vf[((bh*32 + tile)*64 + lanep)*8 + (l & 7)] = f2bf(acc[t][r] + bc);
      }
    }
  }
}

// ---------------- mfma_out: out = X(bf16) @ Wo(bf16)^T + bo, W-tile in LDS ----------
__global__ __launch_bounds__(256, 8) void mfma_out(
    float* __restrict__ ws, const float* __restrict__ bo, float* __restrict__ out)
{
  const short* A = (const short*)(ws + WS_QBF);   // X bf16 (reused region)
  const short* W = (const short*)(ws + WS_WOB);

  __shared__ __align__(16) short Wl[32*WROW];
  const int nb = blockIdx.x * 32;
  stage_w(Wl, W + nb*HIDN);

  const int wid  = threadIdx.x >> 6;
  const int lane = threadIdx.x & 63;
  const int mt = blockIdx.y * 4 + wid;
  const short* aptr = A + (mt*16 + (lane & 15))*HIDN + (lane >> 4)*8;
  const short* wl0  = &Wl[(lane & 15)*WROW + (lane >> 4)*8];

  f32x4 acc[2] = {{0,0,0,0},{0,0,0,0}};
#pragma unroll 4
  for (int k0 = 0; k0 < HIDN; k0 += 32) {
    const bf16x8 af = *reinterpret_cast<const bf16x8*>(aptr + k0);
#pragma unroll
    for (int t = 0; t < 2; ++t)
      acc[t] = __builtin_amdgcn_mfma_f32_16x16x32_bf16(
          af, *reinterpret_cast<const bf16x8*>(wl0 + t*16*WROW + k0), acc[t], 0, 0, 0);
  }

  const int rbase = mt*16 + (lane >> 4)*4;
#pragma unroll
  for (int t = 0; t < 2; ++t) {
    const int c = nb + t*16 + (lane & 15);
    const float bc = bo[c];
#pragma unroll
    for (int r = 0; r < 4; ++r)
      out[(rbase + r)*HIDN + c] = acc[t][r] + bc;
  }
}

// ---------------- attn: paired-rcp energy (SGPR Eq/va), no-max softmax, MFMA PV ------
// grid (32 bh, 16 qt): bid%8 XCD mapping pins bh==XCD (mod 8) -> EK/VF L2-resident.
__global__ __launch_bounds__(1024, 8) void attn_kernel(
    const float* __restrict__ eqB, const float* __restrict__ ekB,
    const short* __restrict__ vfB, const float* __restrict__ va_w,
    float* __restrict__ attn_out, short* __restrict__ xb)
{
  const int bh = blockIdx.x;
  const int qt = blockIdx.y;
  const int tid = threadIdx.x;

  __shared__ __align__(16) short aLb[8][64][8];      // P as bf16 A-fragments
  __shared__ __align__(16) float reds[4][4][4];      // [qgroup][wave][qi]

  const float* EKB = ekB + bh*NL*DHEAD;
  const short* VF  = vfB + bh*32*64*8;

  const int g  = tid >> 8;        // q-group: rows g*4 .. g*4+3 (wave-uniform)
  const int lk = tid & 255;
  const int wv = lk >> 6;
  const int l  = lk & 63;
  const float* EkRow = EKB + lk*DHEAD;
  const int g_u = __builtin_amdgcn_readfirstlane(g);
  const float* EqG = eqB + (bh*NL + qt*16 + g_u*4)*DHEAD;

  float acc[4];
#pragma unroll
  for (int qi = 0; qi < 4; ++qi) acc[qi] = 0.f;

#pragma unroll 1
  for (int d0 = 0; d0 < 64; d0 += 8) {
    const f32x4 ea = *reinterpret_cast<const f32x4*>(EkRow + d0);
    const f32x4 eb = *reinterpret_cast<const f32x4*>(EkRow + d0 + 4);
    const f32x4 vaA = *reinterpret_cast<const f32x4*>(va_w + d0);       // uniform -> SGPR
    const f32x4 vaB = *reinterpret_cast<const f32x4*>(va_w + d0 + 4);
#pragma unroll
    for (int qi = 0; qi < 4; ++qi) {
      const f32x4 qa = *reinterpret_cast<const f32x4*>(EqG + qi*DHEAD + d0);      // uniform
      const f32x4 qb = *reinterpret_cast<const f32x4*>(EqG + qi*DHEAD + d0 + 4);  // uniform
      const float t0 = fmaf(qa.x, ea.x, 1.0f);
      const float t1 = fmaf(qa.y, ea.y, 1.0f);
      const float t2 = fmaf(qa.z, ea.z, 1.0f);
      const float t3 = fmaf(qa.w, ea.w, 1.0f);
      const float t4 = fmaf(qb.x, eb.x, 1.0f);
      const float t5 = fmaf(qb.y, eb.y, 1.0f);
      const float t6 = fmaf(qb.z, eb.z, 1.0f);
      const float t7 = fmaf(qb.w, eb.w, 1.0f);
      float a = acc[qi];
      a = fmaf(fmaf(vaA.x, t1, vaA.y * t0), __builtin_amdgcn_rcpf(t0 * t1), a);
      a = fmaf(fmaf(vaA.z, t3, vaA.w * t2), __builtin_amdgcn_rcpf(t2 * t3), a);
      a = fmaf(fmaf(vaB.x, t5, vaB.y * t4), __builtin_amdgcn_rcpf(t4 * t5), a);
      a = fmaf(fmaf(vaB.z, t7, vaB.w * t6), __builtin_amdgcn_rcpf(t6 * t7), a);
      acc[qi] = a;
    }
  }

  float p[4];
#pragma unroll
  for (int qi = 0; qi < 4; ++qi)
    p[qi] = __builtin_amdgcn_exp2f(acc[qi] * NEG2LOG2E);

#pragma unroll
  for (int qi = 0; qi < 4; ++qi) {
    float s = p[qi];
#pragma unroll
    for (int off = 1; off < 64; off <<= 1)
      s += __shfl_xor(s, off);
    if (l == 0) reds[g][wv][qi] = s;
  }
  {
    const int kb2 = lk >> 5;
    const int lbase = ((lk >> 3) & 3) * 16;
    const int jb = lk & 7;
#pragma unroll
    for (int qi = 0; qi < 4; ++qi)
      aLb[kb2][lbase + g*4 + qi][jb] = f2bf(p[qi]);
  }
  __syncthreads();

  {
    f32x4 s4 = {0.f,0.f,0.f,0.f};
#pragma unroll
    for (int w2 = 0; w2 < 4; ++w2)
      s4 += *reinterpret_cast<const f32x4*>(&reds[g][w2][0]);
    float inv[4];
    inv[0] = __builtin_amdgcn_rcpf(s4.x); inv[1] = __builtin_amdgcn_rcpf(s4.y);
    inv[2] = __builtin_amdgcn_rcpf(s4.z); inv[3] = __builtin_amdgcn_rcpf(s4.w);
#pragma unroll
    for (int qi = 0; qi < 4; ++qi)
      attn_out[(bh*NL + qt*16 + g*4 + qi)*NL + lk] = p[qi] * inv[qi];

    const int wid = tid >> 6;
    if (wid < 4) {
      f32x4 pacc = {0.f,0.f,0.f,0.f};
#pragma unroll
      for (int kb2 = 0; kb2 < 8; ++kb2) {
        const bf16x8 af  = *reinterpret_cast<const bf16x8*>(&aLb[kb2][l][0]);
        const bf16x8 bff = *reinterpret_cast<const bf16x8*>(&VF[((kb2*4 + wid)*64 + l)*8]);
        pacc = __builtin_amdgcn_mfma_f32_16x16x32_bf16(af, bff, pacc, 0, 0, 0);
      }
      const int b_ = bh >> 3, hh = bh & 7;
      const int colv = hh*DHEAD + wid*16 + (l & 15);
#pragma unroll
      for (int r = 0; r < 4; ++r) {
        const int row = (l >> 4)*4 + r;
        const float stot = reds[row>>2][0][row&3] + reds[row>>2][1][row&3]
                         + reds[row>>2][2][row&3] + reds[row>>2][3][row&3];
        xb[(b_*NL + qt*16 + row)*HIDN + colv] = f2bf(pacc[r] * __builtin_amdgcn_rcpf(stot));
      }
    }
  }
}

extern "C" void kernel_launch(void* const* d_in, const int* in_sizes, int n_in,
                              void* d_out, int out_size, void* d_ws, size_t ws_size,
                              hipStream_t stream) {
  const float* q    = (const float*)d_in[0];
  const float* kin  = (const float*)d_in[1];
  const float* v    = (const float*)d_in[2];
  const float* Wq   = (const float*)d_in[3];
  const float* bq   = (const float*)d_in[4];
  const float* Wk   = (const float*)d_in[5];
  const float* bk   = (const float*)d_in[6];
  const float* Wv   = (const float*)d_in[7];
  const float* bv   = (const float*)d_in[8];
  const float* W1   = (const float*)d_in[9];
  const float* b1   = (const float*)d_in[10];
  const float* W2   = (const float*)d_in[11];
  const float* b2   = (const float*)d_in[12];
  const float* va_w = (const float*)d_in[13];
  const float* Wo   = (const float*)d_in[15];
  const float* bo   = (const float*)d_in[16];

  float* out = (float*)d_out;
  float* ws  = (float*)d_ws;
  float* attn = out + NROW*HIDN;   // output 1: attention [B,H,Lq,Lk]

  prep<<<dim3(256, 1, 7), 256, 0, stream>>>(Wq, bq, Wk, bk, W1, b1, W2, b2,
                                            q, kin, v, Wv, Wo, ws);
  mfma_proj<<<dim3(16, 16, 3), 256, 0, stream>>>(ws, bv);
  attn_kernel<<<dim3(32, 16), 1024, 0, stream>>>(
      ws + WS_EQ, ws + WS_EK, (const short*)(ws + WS_VF), va_w,
      attn, (short*)(ws + WS_QBF));
  mfma_out<<<dim3(16, 16), 256, 0, stream>>>(ws, bo, out);
}